// Round 3
// baseline (67.922 us; speedup 1.0000x reference)
//
#include <hip/hip_runtime.h>

// PSRoIPool — raw f32 inputs, f32 compute, bin size via RECIPROCAL-MULTIPLY.
// R13 PASSED (absmax 0.0039): the golden lowers /7 to * fl(1/7). DO NOT
// change the geometry chain — especially `* rcp7` — it is semantics-bearing.
//
// R14: 8 lanes per bin (2 rows x 4 cols), 3-step shfl_xor reduce. 67.65 us.
// R15 perf change: the harness's 256 MiB re-poison fill evicts L2/L3 every
// iteration, so the gather loop runs at HBM-miss latency (~900 cy). The old
// runtime-trip inner loop serialized up to ~20 such epochs per wave
// (load -> waitcnt -> add per iteration). New scheme: each lane does ONE
// aligned float4 load per row (rows are 336 B = 21x16 B, so h*WW + 4k floats
// is always 16B-aligned) over a 16-float window covering the bin width
// (we-ws <= 13 for this input distribution), in a FIXED fully-unrolled
// 5-step row loop (he-hs <= 9). All <=5 loads per lane are independent ->
// single latency epoch. Out-of-window elems masked by exact selects.
// (R16, R17 = R15 resubmitted verbatim: both benches were infra failures —
// "MI355X container failed twice" — no compile/correctness/perf data.)

#define GS 7   // group size G
#define DD 8   // D = C / (G*G)
#define BB 2   // batch
#define HH 50
#define WW 84

__global__ void psroi_kernel(const float* __restrict__ rois,
                             const float* __restrict__ feat,
                             const int*   __restrict__ stride_ptr,
                             float*       __restrict__ out,
                             int nbins) {
    // Single-rounded ops only — no implicit FMA contraction (semantics).
    #pragma clang fp contract(off)

    int t = blockIdx.x * blockDim.x + threadIdx.x;
    int bin  = t >> 3;        // 8 lanes per bin
    int lane = t & 7;
    if (bin >= nbins) return;

    int j = bin % GS;
    int i = (bin / GS) % GS;
    int d = (bin / (GS * GS)) % DD;
    int n = bin / (GS * GS * DD);

    float scale = 1.0f / (float)(*stride_ptr);   // 1/16 exact

    const float* r = rois + (size_t)n * 5;

    // batch index (0/1); clamp defensively against OOB.
    int b = (int)r[0];
    b = b < 0 ? 0 : (b > (BB - 1) ? (BB - 1) : b);

    // Geometry in f32 on raw inputs (np.round = half-even = rintf).
    float xs = rintf(r[1]) * scale;
    float ys = rintf(r[2]) * scale;
    float xe = (rintf(r[3]) + 1.0f) * scale;
    float ye = (rintf(r[4]) + 1.0f) * scale;

    // Semantics-critical: golden computes /7 as multiply by fl(1/7).
    const float rcp7 = 1.0f / 7.0f;
    float bin_w = fmaxf(xe - xs, 0.1f) * rcp7;
    float bin_h = fmaxf(ye - ys, 0.1f) * rcp7;

    float jf = (float)j;
    float fi = (float)i;

    float wstart = fminf(fmaxf(floorf(jf * bin_w + xs), 0.0f), (float)WW);
    float wend   = fminf(fmaxf(ceilf((jf + 1.0f) * bin_w + xs), 0.0f), (float)WW);
    float hstart = fminf(fmaxf(floorf(fi * bin_h + ys), 0.0f), (float)HH);
    float hend   = fminf(fmaxf(ceilf((fi + 1.0f) * bin_h + ys), 0.0f), (float)HH);

    float area = fmaxf((hend - hstart) * (wend - wstart), 1.0f);

    int hs = (int)hstart, he = (int)hend;
    int ws = (int)wstart, we = (int)wend;

    int c = (d * GS + i) * GS + j;   // position-sensitive channel
    const float* fbase = feat + ((size_t)b * (DD * GS * GS) + c) * (HH * WW);

    // 2x4 lane tile: lh in {0,1} row parity, lw in {0..3} float4 column.
    int lh = lane >> 2;
    int lw = lane & 3;

    float sum = 0.0f;

    if (hs < he && ws < we) {
        int wa0 = ws & ~3;                       // 16B-aligned window start
        if (we - wa0 > 16 || he - hs > 10) {
            // Pathological bin (cannot occur with bench geometry: bin_w<=11.6
            // -> we-ws<=13; bin_h<=6.9 -> he-hs<=9). Generic scalar path.
            for (int h = hs + lh; h < he; h += 2) {
                const float* row = fbase + h * WW;
                for (int w = ws + lw; w < we; w += 4) sum += row[w];
            }
        } else {
            int wa = wa0 > (WW - 16) ? (WW - 16) : wa0;  // keep window in-row
            int w0 = wa + lw * 4;                         // this lane's float4
            // Per-element width masks (loop-invariant; exact selects).
            bool m0 = (w0 + 0 >= ws) & (w0 + 0 < we);
            bool m1 = (w0 + 1 >= ws) & (w0 + 1 < we);
            bool m2 = (w0 + 2 >= ws) & (w0 + 2 < we);
            bool m3 = (w0 + 3 >= ws) & (w0 + 3 < we);
            #pragma unroll
            for (int k = 0; k < 5; ++k) {
                int h  = hs + lh + 2 * k;
                bool hv = h < he;
                int hc = hv ? h : hs;                 // hs is always a valid row
                const float4 v =
                    *reinterpret_cast<const float4*>(fbase + hc * WW + w0);
                float a0 = (hv & m0) ? v.x : 0.0f;
                float a1 = (hv & m1) ? v.y : 0.0f;
                float a2 = (hv & m2) ? v.z : 0.0f;
                float a3 = (hv & m3) ? v.w : 0.0f;
                sum += (a0 + a1) + (a2 + a3);
            }
        }
    }

    // Reduce across the 8-lane group (xor masks stay within the group).
    sum += __shfl_xor(sum, 1, 64);
    sum += __shfl_xor(sum, 2, 64);
    sum += __shfl_xor(sum, 4, 64);

    if (lane == 0) out[bin] = sum / area;
}

extern "C" void kernel_launch(void* const* d_in, const int* in_sizes, int n_in,
                              void* d_out, int out_size, void* d_ws, size_t ws_size,
                              hipStream_t stream) {
    const float* rois   = (const float*)d_in[0];
    const float* feat   = (const float*)d_in[1];
    const int*   stride = (const int*)d_in[2];
    float*       out    = (float*)d_out;

    int nbins = out_size;               // N * D * G * G = 50176
    int threads = nbins * 8;
    int block = 256;
    int grid  = (threads + block - 1) / block;   // 1568 blocks
    psroi_kernel<<<grid, block, 0, stream>>>(rois, feat, stride, out, nbins);
}